// Round 4
// baseline (752.670 us; speedup 1.0000x reference)
//
#include <hip/hip_runtime.h>

// Problem constants (fixed by reference):
#define F_DIM  4096
#define NROUNDS 12
#define GM     8192   // B*S
#define GN     4096   // F_OUT
#define GK     4096   // F_IN
#define BK2    128            // i8 K-tile (128 B row slice, same bytes as bf16 BK=64)
#define NIT2   (GK / BK2)     // 32

typedef int  int4v __attribute__((ext_vector_type(4)));
typedef signed char schar;

typedef __attribute__((address_space(3))) void lds_void;
typedef const __attribute__((address_space(1))) void glob_void;

__device__ __forceinline__ unsigned ordf(float f) {
    unsigned u = __float_as_uint(f);
    return (u & 0x80000000u) ? ~u : (u | 0x80000000u);
}
__device__ __forceinline__ float unordf(unsigned u) {
    unsigned v = (u & 0x80000000u) ? (u & 0x7fffffffu) : ~u;
    return __uint_as_float(v);
}

__global__ void init_mm_kernel(unsigned* mm) {
    if (threadIdx.x < 4) mm[threadIdx.x] = (threadIdx.x & 1) ? 0u : 0xFFFFFFFFu;
}

// ---------------------------------------------------------------------------
// R4: fused round-pair metadata. For fused pair rp (rounds 2rp, 2rp+1) and
// output pair j: out = M2 * (c_a, c_b) with c_a = Ma.(v[i0],v[i1]),
// c_b = Mb.(v[i2],v[i3]) -- exactly the two successive per-round expressions,
// so arithmetic is value-identical to running the rounds separately.
// fidx holds sig()-transformed LDS indices; fmaC = (Ma.x,Ma.y,Mb.x,Mb.y);
// fm2 = round-(2rp+1) 2x2 block.
// ---------------------------------------------------------------------------
__global__ __launch_bounds__(256)
void fuse_meta_kernel(const int*   __restrict__ perms,
                      const float* __restrict__ mats,
                      int4v*  __restrict__ fidx,
                      float4* __restrict__ fmaC,
                      float4* __restrict__ fm2)
{
    const int g = blockIdx.x * 256 + threadIdx.x;   // rp*2048 + j
    if (g >= 6 * 2048) return;
    const int rp = g >> 11, j = g & 2047;
    const int r0 = 2 * rp, r1 = 2 * rp + 1;
    const int a = perms[r1 * 4096 + 2 * j];
    const int b = perms[r1 * 4096 + 2 * j + 1];
    const int i0 = perms[r0 * 4096 + 2 * (a >> 1)];
    const int i1 = perms[r0 * 4096 + 2 * (a >> 1) + 1];
    const int i2 = perms[r0 * 4096 + 2 * (b >> 1)];
    const int i3 = perms[r0 * 4096 + 2 * (b >> 1) + 1];
    const float4 Ma = ((const float4*)mats)[r0 * 2048 + (a >> 1)];
    const float4 Mb = ((const float4*)mats)[r0 * 2048 + (b >> 1)];
    float4 mc;
    mc.x = (a & 1) ? Ma.z : Ma.x;  mc.y = (a & 1) ? Ma.w : Ma.y;
    mc.z = (b & 1) ? Mb.z : Mb.x;  mc.w = (b & 1) ? Mb.w : Mb.y;
    int4v s;
    s[0] = (i0 >> 1) + ((i0 & 1) << 11);
    s[1] = (i1 >> 1) + ((i1 & 1) << 11);
    s[2] = (i2 >> 1) + ((i2 & 1) << 11);
    s[3] = (i3 >> 1) + ((i3 & 1) << 11);
    fidx[g] = s;
    fmaC[g] = mc;
    fm2[g]  = ((const float4*)mats)[r1 * 2048 + j];
}

// ---------------------------------------------------------------------------
// Rotation: 4 rows/block, FEATURE-MAJOR LDS. buf[sig(f)] = float4 of rows 0..3
// at feature f, sig(f) = (f>>1) + (f&1)*2048. One ds_read_b128 gathers 4 rows.
// 256 threads/block (R2 lesson: 512t halves per-wave gather ILP -> 1.7x
// slower). R4: rounds processed as FUSED PAIRS via precomputed metadata:
// per pair 32 gathers (same as before) but writes 32->16 and barriers 4->2.
// Block barriers: 23 -> 11. Last fused pair computes in regs and stores
// directly (no LDS round-trip). W+X combined in one launch.
// ---------------------------------------------------------------------------
__global__ __launch_bounds__(256, 2)
void rotate_store_kernel(const float* __restrict__ xsrc,
                         const float* __restrict__ wsrc,
                         const int4v*  __restrict__ fidx,
                         const float4* __restrict__ fmaC,
                         const float4* __restrict__ fm2,
                         unsigned*    __restrict__ mm,
                         float*       __restrict__ xdst,
                         float*       __restrict__ wdst)
{
    __shared__ float4 buf[F_DIM];   // 64 KB
    const int t = threadIdx.x;
    const int b = blockIdx.x;
    const bool isW = b < (GN / 4);
    const float* __restrict__ src = isW ? wsrc : xsrc;
    float* __restrict__ dst = isW ? wdst : xdst;
    unsigned* mmp = mm + (isW ? 2 : 0);
    const size_t r0 = (size_t)(isW ? b : b - GN / 4) * 4;

    const float2* s0 = (const float2*)(src + (r0 + 0) * F_DIM);
    const float2* s1 = (const float2*)(src + (r0 + 1) * F_DIM);
    const float2* s2 = (const float2*)(src + (r0 + 2) * F_DIM);
    const float2* s3 = (const float2*)(src + (r0 + 3) * F_DIM);
    #pragma unroll
    for (int q = 0; q < 8; ++q) {
        const int e = t + q * 256;
        float2 a = s0[e], b2 = s1[e], c = s2[e], d = s3[e];
        buf[e]        = make_float4(a.x, b2.x, c.x, d.x);
        buf[e + 2048] = make_float4(a.y, b2.y, c.y, d.y);
    }
    __syncthreads();

    int4v  iA[8], iB[8];
    float4 aA[8], aB[8], mA[8], mB[8];
    #pragma unroll
    for (int q = 0; q < 8; ++q) {
        int k = t + q * 256;
        iA[q] = fidx[k]; aA[q] = fmaC[k]; mA[q] = fm2[k];
    }

    // fused pairs 0..3 (two per loop iteration, A/B meta double-buffer)
    #pragma unroll 1
    for (int fp = 0; fp < 4; fp += 2) {
        float4 o0[8], o1[8];
        #pragma unroll
        for (int q = 0; q < 8; ++q) {
            int4v ix = iA[q];
            float4 A0 = buf[ix[0]], A1 = buf[ix[1]];
            float4 B0 = buf[ix[2]], B1 = buf[ix[3]];
            float4 ma = aA[q], m2 = mA[q];
            float4 ca = make_float4(ma.x*A0.x + ma.y*A1.x, ma.x*A0.y + ma.y*A1.y,
                                    ma.x*A0.z + ma.y*A1.z, ma.x*A0.w + ma.y*A1.w);
            float4 cb = make_float4(ma.z*B0.x + ma.w*B1.x, ma.z*B0.y + ma.w*B1.y,
                                    ma.z*B0.z + ma.w*B1.z, ma.z*B0.w + ma.w*B1.w);
            o0[q] = make_float4(m2.x*ca.x + m2.y*cb.x, m2.x*ca.y + m2.y*cb.y,
                                m2.x*ca.z + m2.y*cb.z, m2.x*ca.w + m2.y*cb.w);
            o1[q] = make_float4(m2.z*ca.x + m2.w*cb.x, m2.z*ca.y + m2.w*cb.y,
                                m2.z*ca.z + m2.w*cb.z, m2.z*ca.w + m2.w*cb.w);
        }
        {
            const size_t base = (size_t)(fp + 1) * 2048;
            #pragma unroll
            for (int q = 0; q < 8; ++q) {
                size_t k = base + t + q * 256;
                iB[q] = fidx[k]; aB[q] = fmaC[k]; mB[q] = fm2[k];
            }
        }
        __syncthreads();
        #pragma unroll
        for (int q = 0; q < 8; ++q) {
            const int k = t + q * 256;
            buf[k]        = o0[q];
            buf[k + 2048] = o1[q];
        }
        __syncthreads();

        #pragma unroll
        for (int q = 0; q < 8; ++q) {
            int4v ix = iB[q];
            float4 A0 = buf[ix[0]], A1 = buf[ix[1]];
            float4 B0 = buf[ix[2]], B1 = buf[ix[3]];
            float4 ma = aB[q], m2 = mB[q];
            float4 ca = make_float4(ma.x*A0.x + ma.y*A1.x, ma.x*A0.y + ma.y*A1.y,
                                    ma.x*A0.z + ma.y*A1.z, ma.x*A0.w + ma.y*A1.w);
            float4 cb = make_float4(ma.z*B0.x + ma.w*B1.x, ma.z*B0.y + ma.w*B1.y,
                                    ma.z*B0.z + ma.w*B1.z, ma.z*B0.w + ma.w*B1.w);
            o0[q] = make_float4(m2.x*ca.x + m2.y*cb.x, m2.x*ca.y + m2.y*cb.y,
                                m2.x*ca.z + m2.y*cb.z, m2.x*ca.w + m2.y*cb.w);
            o1[q] = make_float4(m2.z*ca.x + m2.w*cb.x, m2.z*ca.y + m2.w*cb.y,
                                m2.z*ca.z + m2.w*cb.z, m2.z*ca.w + m2.w*cb.w);
        }
        {
            const size_t base = (size_t)(fp + 2) * 2048;
            #pragma unroll
            for (int q = 0; q < 8; ++q) {
                size_t k = base + t + q * 256;
                iA[q] = fidx[k]; aA[q] = fmaC[k]; mA[q] = fm2[k];
            }
        }
        __syncthreads();
        #pragma unroll
        for (int q = 0; q < 8; ++q) {
            const int k = t + q * 256;
            buf[k]        = o0[q];
            buf[k + 2048] = o1[q];
        }
        __syncthreads();
    }

    // fused pair 4 (meta in A), prefetch pair 5 into B
    {
        float4 o0[8], o1[8];
        #pragma unroll
        for (int q = 0; q < 8; ++q) {
            int4v ix = iA[q];
            float4 A0 = buf[ix[0]], A1 = buf[ix[1]];
            float4 B0 = buf[ix[2]], B1 = buf[ix[3]];
            float4 ma = aA[q], m2 = mA[q];
            float4 ca = make_float4(ma.x*A0.x + ma.y*A1.x, ma.x*A0.y + ma.y*A1.y,
                                    ma.x*A0.z + ma.y*A1.z, ma.x*A0.w + ma.y*A1.w);
            float4 cb = make_float4(ma.z*B0.x + ma.w*B1.x, ma.z*B0.y + ma.w*B1.y,
                                    ma.z*B0.z + ma.w*B1.z, ma.z*B0.w + ma.w*B1.w);
            o0[q] = make_float4(m2.x*ca.x + m2.y*cb.x, m2.x*ca.y + m2.y*cb.y,
                                m2.x*ca.z + m2.y*cb.z, m2.x*ca.w + m2.y*cb.w);
            o1[q] = make_float4(m2.z*ca.x + m2.w*cb.x, m2.z*ca.y + m2.w*cb.y,
                                m2.z*ca.z + m2.w*cb.z, m2.z*ca.w + m2.w*cb.w);
        }
        {
            const size_t base = (size_t)5 * 2048;
            #pragma unroll
            for (int q = 0; q < 8; ++q) {
                size_t k = base + t + q * 256;
                iB[q] = fidx[k]; aB[q] = fmaC[k]; mB[q] = fm2[k];
            }
        }
        __syncthreads();
        #pragma unroll
        for (int q = 0; q < 8; ++q) {
            const int k = t + q * 256;
            buf[k]        = o0[q];
            buf[k + 2048] = o1[q];
        }
        __syncthreads();
    }

    // fused pair 5 (rounds 10+11) fused with store: compute in regs, store
    // directly. o0/o1 are exactly what the old code wrote/re-read via LDS ->
    // bit-identical output and min/max.
    float lmin = __FLT_MAX__, lmax = -__FLT_MAX__;
    #pragma unroll
    for (int q = 0; q < 8; ++q) {
        int4v ix = iB[q];
        float4 A0 = buf[ix[0]], A1 = buf[ix[1]];
        float4 B0 = buf[ix[2]], B1 = buf[ix[3]];
        float4 ma = aB[q], m2 = mB[q];
        float4 ca = make_float4(ma.x*A0.x + ma.y*A1.x, ma.x*A0.y + ma.y*A1.y,
                                ma.x*A0.z + ma.y*A1.z, ma.x*A0.w + ma.y*A1.w);
        float4 cb = make_float4(ma.z*B0.x + ma.w*B1.x, ma.z*B0.y + ma.w*B1.y,
                                ma.z*B0.z + ma.w*B1.z, ma.z*B0.w + ma.w*B1.w);
        float4 f0 = make_float4(m2.x*ca.x + m2.y*cb.x, m2.x*ca.y + m2.y*cb.y,
                                m2.x*ca.z + m2.y*cb.z, m2.x*ca.w + m2.y*cb.w);
        float4 f1 = make_float4(m2.z*ca.x + m2.w*cb.x, m2.z*ca.y + m2.w*cb.y,
                                m2.z*ca.z + m2.w*cb.z, m2.z*ca.w + m2.w*cb.w);
        lmin = fminf(lmin, fminf(fminf(f0.x, f0.y), fminf(f0.z, f0.w)));
        lmin = fminf(lmin, fminf(fminf(f1.x, f1.y), fminf(f1.z, f1.w)));
        lmax = fmaxf(lmax, fmaxf(fmaxf(f0.x, f0.y), fmaxf(f0.z, f0.w)));
        lmax = fmaxf(lmax, fmaxf(fmaxf(f1.x, f1.y), fmaxf(f1.z, f1.w)));
        const int e = t + q * 256;
        ((float2*)(dst + (r0 + 0) * F_DIM))[e] = make_float2(f0.x, f1.x);
        ((float2*)(dst + (r0 + 1) * F_DIM))[e] = make_float2(f0.y, f1.y);
        ((float2*)(dst + (r0 + 2) * F_DIM))[e] = make_float2(f0.z, f1.z);
        ((float2*)(dst + (r0 + 3) * F_DIM))[e] = make_float2(f0.w, f1.w);
    }
    #pragma unroll
    for (int off = 32; off > 0; off >>= 1) {
        lmin = fminf(lmin, __shfl_down(lmin, off));
        lmax = fmaxf(lmax, __shfl_down(lmax, off));
    }
    if ((t & 63) == 0) {
        atomicMin(&mmp[0], ordf(lmin));
        atomicMax(&mmp[1], ordf(lmax));
    }
}

// ---------------------------------------------------------------------------
// Quantize one row per block from exact fp32: p = clip(rint((f-lo)/scale),0,255)
// (IEEE div + RNE = jnp.round path, validated previously). Store s8 = p-128 and
// the integer row-sum of s8 (needed by the i8 GEMM epilogue).
// ---------------------------------------------------------------------------
__global__ __launch_bounds__(256)
void quant_row_kernel(const float* __restrict__ src,
                      schar*       __restrict__ dst,
                      int*         __restrict__ rowsum,
                      const unsigned* __restrict__ mm, int sel)
{
    const int row = blockIdx.x, t = threadIdx.x;
    const float lo = unordf(mm[sel]);
    const float hi = unordf(mm[sel + 1]);
    const float scale = (hi - lo) / 255.0f;
    const float4* s = (const float4*)(src + (size_t)row * F_DIM);
    unsigned* d = (unsigned*)(dst + (size_t)row * F_DIM);
    int sum = 0;
    #pragma unroll
    for (int j = 0; j < 4; ++j) {
        const int c = t + 256 * j;
        float4 v = s[c];
        int p0 = (int)fminf(fmaxf(rintf((v.x - lo) / scale), 0.0f), 255.0f);
        int p1 = (int)fminf(fmaxf(rintf((v.y - lo) / scale), 0.0f), 255.0f);
        int p2 = (int)fminf(fmaxf(rintf((v.z - lo) / scale), 0.0f), 255.0f);
        int p3 = (int)fminf(fmaxf(rintf((v.w - lo) / scale), 0.0f), 255.0f);
        sum += p0 + p1 + p2 + p3 - 512;   // Σ (p-128)
        unsigned pack = ((unsigned)(p0 - 128) & 0xffu)
                      | (((unsigned)(p1 - 128) & 0xffu) << 8)
                      | (((unsigned)(p2 - 128) & 0xffu) << 16)
                      | (((unsigned)(p3 - 128) & 0xffu) << 24);
        d[c] = pack;
    }
    #pragma unroll
    for (int off = 32; off > 0; off >>= 1) sum += __shfl_down(sum, off);
    __shared__ int part[4];
    if ((t & 63) == 0) part[t >> 6] = sum;
    __syncthreads();
    if (t == 0) rowsum[row] = part[0] + part[1] + part[2] + part[3];
}

// ---------------------------------------------------------------------------
// i8 GEMM: C = dequant(A) * dequant(B)^T + bias, expanded exactly:
//   C[m,n] = ax*aw*Σ sx*sw + ax*cw*Rx[m] + aw*cx*Rw[n] + K*cx*cw + bias[n]
// 128x128 tile, BK2=128 (identical 128 B row-slice / 16 B-chunk XOR-swizzled
// LDS byte layout as the proven bf16 BK=64 kernel; NIT halves to 32).
// mfma_i32_16x16x64_i8: lane l holds A row=l&15, k=(l>>4)*16+j (16 B).
// ---------------------------------------------------------------------------
__global__ __launch_bounds__(256)
void gemm_i8_bias_kernel(const schar* __restrict__ A,
                         const schar* __restrict__ B,
                         const float* __restrict__ bias,
                         const int*   __restrict__ Rx,
                         const int*   __restrict__ Rw,
                         const unsigned* __restrict__ mm,
                         float*       __restrict__ C)
{
    __shared__ alignas(16) schar As[128 * 8 * 16];  // 16 KB: slot = row*8 + c
    __shared__ alignas(16) schar Bs[128 * 8 * 16];  // 16 KB
    const int t = threadIdx.x;
    // supertile: 8 consecutive mb x 32 nb per 256-block group
    const int bid = blockIdx.x;
    const int mb = (bid >> 8) * 8 + (bid & 7);
    const int nb = (bid >> 3) & 31;
    const int lane = t & 63, wv = t >> 6;
    const int wm = (wv & 1) * 64, wn = (wv >> 1) * 64;
    const int rr = lane & 15, kc = lane >> 4;

    const int srow = t >> 3;                     // row within 32-row group
    const int cg   = (t & 7) ^ (srow & 7);       // global 16B chunk (swizzled)
    const schar* pa = A + ((size_t)(mb * 128 + srow) * GK) + cg * 16;
    const schar* pb = B + ((size_t)(nb * 128 + srow) * GK) + cg * 16;

    int4v acc[4][4];
    const int4v zz = {0, 0, 0, 0};
    #pragma unroll
    for (int mi = 0; mi < 4; ++mi)
        #pragma unroll
        for (int ni = 0; ni < 4; ++ni)
            acc[mi][ni] = zz;

    auto stage = [&](int k0) {
        #pragma unroll
        for (int j = 0; j < 4; ++j) {
            __builtin_amdgcn_global_load_lds(
                (glob_void*)(pa + (size_t)j * 32 * GK + k0),
                (lds_void*)&As[(size_t)(wv * 64 + 256 * j) * 16], 16, 0, 0);
            __builtin_amdgcn_global_load_lds(
                (glob_void*)(pb + (size_t)j * 32 * GK + k0),
                (lds_void*)&Bs[(size_t)(wv * 64 + 256 * j) * 16], 16, 0, 0);
        }
    };

    stage(0);
    #pragma unroll 1
    for (int it = 0; it < NIT2; ++it) {
        __syncthreads();   // staging of tile `it` complete

        int4v af[2][4], bfr[2][4];
        #pragma unroll
        for (int kk = 0; kk < 2; ++kk) {
            #pragma unroll
            for (int mi = 0; mi < 4; ++mi)
                af[kk][mi] = *(const int4v*)
                    &As[(size_t)((wm + mi * 16 + rr) * 8 + ((kk * 4 + kc) ^ (rr & 7))) * 16];
            #pragma unroll
            for (int ni = 0; ni < 4; ++ni)
                bfr[kk][ni] = *(const int4v*)
                    &Bs[(size_t)((wn + ni * 16 + rr) * 8 + ((kk * 4 + kc) ^ (rr & 7))) * 16];
        }
        __syncthreads();   // all waves done reading -> LDS free for restage

        if (it + 1 < NIT2) stage((it + 1) * BK2);   // hides under MFMAs below

        #pragma unroll
        for (int kk = 0; kk < 2; ++kk)
            #pragma unroll
            for (int mi = 0; mi < 4; ++mi)
                #pragma unroll
                for (int ni = 0; ni < 4; ++ni)
                    acc[mi][ni] = __builtin_amdgcn_mfma_i32_16x16x64_i8(
                        af[kk][mi], bfr[kk][ni], acc[mi][ni], 0, 0, 0);
    }

    // epilogue: dequant expansion in fp32
    const float lox = unordf(mm[0]), hix = unordf(mm[1]);
    const float low = unordf(mm[2]), hiw = unordf(mm[3]);
    const float ax = (hix - lox) / 255.0f, aw = (hiw - low) / 255.0f;
    const float cx = 128.0f * ax + lox, cw = 128.0f * aw + low;
    const float sxw = ax * aw;
    const float kcc = (float)GK * cx * cw;
    const float axcw = ax * cw, awcx = aw * cx;

    float colt[4];
    #pragma unroll
    for (int ni = 0; ni < 4; ++ni) {
        const int col = nb * 128 + wn + ni * 16 + rr;
        colt[ni] = awcx * (float)Rw[col] + kcc + bias[col];
    }
    float rowt[4][4];
    #pragma unroll
    for (int mi = 0; mi < 4; ++mi)
        #pragma unroll
        for (int r = 0; r < 4; ++r)
            rowt[mi][r] = axcw * (float)Rx[mb * 128 + wm + mi * 16 + kc * 4 + r];

    // C/D layout: row-in-16 = kc*4 + reg, col-in-16 = rr (dtype-independent)
    #pragma unroll
    for (int mi = 0; mi < 4; ++mi) {
        #pragma unroll
        for (int ni = 0; ni < 4; ++ni) {
            const int col = nb * 128 + wn + ni * 16 + rr;
            #pragma unroll
            for (int r = 0; r < 4; ++r) {
                const int row = mb * 128 + wm + mi * 16 + kc * 4 + r;
                C[(size_t)row * GN + col] =
                    sxw * (float)acc[mi][ni][r] + rowt[mi][r] + colt[ni];
            }
        }
    }
}

extern "C" void kernel_launch(void* const* d_in, const int* in_sizes, int n_in,
                              void* d_out, int out_size, void* d_ws, size_t ws_size,
                              hipStream_t stream)
{
    (void)in_sizes; (void)n_in; (void)out_size; (void)ws_size;
    const float* x     = (const float*)d_in[0];
    const float* w     = (const float*)d_in[1];
    const float* bias  = (const float*)d_in[2];
    const float* mats  = (const float*)d_in[3];
    const int*   perms = (const int*)d_in[4];
    float* out = (float*)d_out;

    // ws layout (<= 96 MiB budget, proven):
    //   [0,64M):   w_rot fp32 (64 MiB), dead after quant_w; then reused:
    //              [0,32M) xq8 int8, [32M,+32K) Rx
    //   [64M,80M): wq8 int8 (16 MiB)
    //   [80M,+16K): Rw
    //   [81M,+16B): mm
    //   [82M,+576K): fused round-pair metadata (fidx | fmaC | fm2)
    // d_out: x_rot fp32 (exactly 128 MiB), dead after quant_x; GEMM writes C.
    char* ws = (char*)d_ws;
    float*    wrot = (float*)ws;
    schar*    xq8  = (schar*)ws;
    int*      Rx   = (int*)(ws + (size_t)32 * 1024 * 1024);
    schar*    wq8  = (schar*)(ws + (size_t)64 * 1024 * 1024);
    int*      Rw   = (int*)(ws + (size_t)80 * 1024 * 1024);
    unsigned* mm   = (unsigned*)(ws + (size_t)81 * 1024 * 1024);
    int4v*    fidx = (int4v*)(ws + (size_t)82 * 1024 * 1024);
    float4*   fmaC = (float4*)((char*)fidx + 6 * 2048 * sizeof(int4v));
    float4*   fm2  = (float4*)((char*)fmaC + 6 * 2048 * sizeof(float4));
    float*    xrot = out;

    init_mm_kernel<<<1, 64, 0, stream>>>(mm);
    fuse_meta_kernel<<<(6 * 2048) / 256, 256, 0, stream>>>(perms, mats, fidx, fmaC, fm2);
    // combined W+X rotate: blocks [0, GN/4) = W, [GN/4, GN/4+GM/4) = X
    rotate_store_kernel<<<GN / 4 + GM / 4, 256, 0, stream>>>(
        x, w, fidx, fmaC, fm2, mm, xrot, wrot);
    // quant_w first: it reads wrot before quant_x overwrites that region (xq8)
    quant_row_kernel<<<GN, 256, 0, stream>>>(wrot, wq8, Rw, mm, 2);
    quant_row_kernel<<<GM, 256, 0, stream>>>(xrot, xq8, Rx, mm, 0);
    gemm_i8_bias_kernel<<<GM / 128 * GN / 128, 256, 0, stream>>>(
        xq8, wq8, bias, Rx, Rw, mm, out);
}

// Round 5
// 698.243 us; speedup vs baseline: 1.0779x; 1.0779x over previous
//
#include <hip/hip_runtime.h>

// Problem constants (fixed by reference):
#define F_DIM  4096
#define NROUNDS 12
#define GM     8192   // B*S
#define GN     4096   // F_OUT
#define GK     4096   // F_IN
#define BK2    128            // i8 K-tile (128 B row slice, same bytes as bf16 BK=64)
#define NIT2   (GK / BK2)     // 32

typedef int  int4v __attribute__((ext_vector_type(4)));
typedef signed char schar;

typedef __attribute__((address_space(3))) void lds_void;
typedef const __attribute__((address_space(1))) void glob_void;

__device__ __forceinline__ unsigned ordf(float f) {
    unsigned u = __float_as_uint(f);
    return (u & 0x80000000u) ? ~u : (u | 0x80000000u);
}
__device__ __forceinline__ float unordf(unsigned u) {
    unsigned v = (u & 0x80000000u) ? (u & 0x7fffffffu) : ~u;
    return __uint_as_float(v);
}

__global__ void init_mm_kernel(unsigned* mm) {
    if (threadIdx.x < 4) mm[threadIdx.x] = (threadIdx.x & 1) ? 0u : 0xFFFFFFFFu;
}

// ---------------------------------------------------------------------------
// Fused round-pair metadata (R4, value-identical fusion — validated). For
// fused pair rp (rounds 2rp, 2rp+1), output pair j: out = M2 * (c_a, c_b),
// c_a = Ma.(v[i0],v[i1]), c_b = Mb.(v[i2],v[i3]) — exactly the two successive
// per-round expressions. fidx holds sig()-transformed LDS indices;
// fmaC = (Ma row for a, Mb row for b); fm2 = round-(2rp+1) 2x2 block.
// ---------------------------------------------------------------------------
__global__ __launch_bounds__(256)
void fuse_meta_kernel(const int*   __restrict__ perms,
                      const float* __restrict__ mats,
                      int4v*  __restrict__ fidx,
                      float4* __restrict__ fmaC,
                      float4* __restrict__ fm2)
{
    const int g = blockIdx.x * 256 + threadIdx.x;   // rp*2048 + j
    if (g >= 6 * 2048) return;
    const int rp = g >> 11, j = g & 2047;
    const int r0 = 2 * rp, r1 = 2 * rp + 1;
    const int a = perms[r1 * 4096 + 2 * j];
    const int b = perms[r1 * 4096 + 2 * j + 1];
    const int i0 = perms[r0 * 4096 + 2 * (a >> 1)];
    const int i1 = perms[r0 * 4096 + 2 * (a >> 1) + 1];
    const int i2 = perms[r0 * 4096 + 2 * (b >> 1)];
    const int i3 = perms[r0 * 4096 + 2 * (b >> 1) + 1];
    const float4 Ma = ((const float4*)mats)[r0 * 2048 + (a >> 1)];
    const float4 Mb = ((const float4*)mats)[r0 * 2048 + (b >> 1)];
    float4 mc;
    mc.x = (a & 1) ? Ma.z : Ma.x;  mc.y = (a & 1) ? Ma.w : Ma.y;
    mc.z = (b & 1) ? Mb.z : Mb.x;  mc.w = (b & 1) ? Mb.w : Mb.y;
    int4v s;
    s[0] = (i0 >> 1) + ((i0 & 1) << 11);
    s[1] = (i1 >> 1) + ((i1 & 1) << 11);
    s[2] = (i2 >> 1) + ((i2 & 1) << 11);
    s[3] = (i3 >> 1) + ((i3 & 1) << 11);
    fidx[g] = s;
    fmaC[g] = mc;
    fm2[g]  = ((const float4*)mats)[r1 * 2048 + j];
}

// ---------------------------------------------------------------------------
// Rotation: 4 rows/block, FEATURE-MAJOR LDS. buf[sig(f)] = float4 of rows 0..3
// at feature f. 256 threads (R2: 512t halves per-wave gather ILP). Rounds run
// as FUSED PAIRS (R4): per pair 32 gathers, 16 writes, 2 barriers (23 -> 11
// barriers/block). R5: spill fix — R4 prefetched ALL meta (192 VGPRs) under a
// 128-VGPR cap -> ~370 MB scratch spills. Now only the 4 LDS indices are
// prefetched one pair ahead (32 VGPRs, needed to issue phase-start ds_reads);
// fmaC/fm2 are loaded inline from L2 (589 KB, resident) and overlap the
// gathers. Last pair computes in regs and stores directly. W+X in one launch.
// ---------------------------------------------------------------------------
__global__ __launch_bounds__(256)
void rotate_store_kernel(const float* __restrict__ xsrc,
                         const float* __restrict__ wsrc,
                         const int4v*  __restrict__ fidx,
                         const float4* __restrict__ fmaC,
                         const float4* __restrict__ fm2,
                         unsigned*    __restrict__ mm,
                         float*       __restrict__ xdst,
                         float*       __restrict__ wdst)
{
    __shared__ float4 buf[F_DIM];   // 64 KB
    const int t = threadIdx.x;
    const int b = blockIdx.x;
    const bool isW = b < (GN / 4);
    const float* __restrict__ src = isW ? wsrc : xsrc;
    float* __restrict__ dst = isW ? wdst : xdst;
    unsigned* mmp = mm + (isW ? 2 : 0);
    const size_t r0 = (size_t)(isW ? b : b - GN / 4) * 4;

    const float2* s0 = (const float2*)(src + (r0 + 0) * F_DIM);
    const float2* s1 = (const float2*)(src + (r0 + 1) * F_DIM);
    const float2* s2 = (const float2*)(src + (r0 + 2) * F_DIM);
    const float2* s3 = (const float2*)(src + (r0 + 3) * F_DIM);
    #pragma unroll
    for (int q = 0; q < 8; ++q) {
        const int e = t + q * 256;
        float2 a = s0[e], b2 = s1[e], c = s2[e], d = s3[e];
        buf[e]        = make_float4(a.x, b2.x, c.x, d.x);
        buf[e + 2048] = make_float4(a.y, b2.y, c.y, d.y);
    }
    __syncthreads();

    // index prefetch only (32 VGPRs) — the phase-critical ds_read addresses
    int4v iN[8];
    #pragma unroll
    for (int q = 0; q < 8; ++q) iN[q] = fidx[t + q * 256];

    #pragma unroll 1
    for (int fp = 0; fp < 5; ++fp) {
        const float4* ap = fmaC + (size_t)fp * 2048;
        const float4* mp = fm2  + (size_t)fp * 2048;
        float4 o0[8], o1[8];
        #pragma unroll
        for (int q = 0; q < 8; ++q) {
            const int k = t + q * 256;
            int4v ix = iN[q];
            float4 A0 = buf[ix[0]], A1 = buf[ix[1]];
            float4 B0 = buf[ix[2]], B1 = buf[ix[3]];
            float4 ma = ap[k], m2 = mp[k];
            float4 ca = make_float4(ma.x*A0.x + ma.y*A1.x, ma.x*A0.y + ma.y*A1.y,
                                    ma.x*A0.z + ma.y*A1.z, ma.x*A0.w + ma.y*A1.w);
            float4 cb = make_float4(ma.z*B0.x + ma.w*B1.x, ma.z*B0.y + ma.w*B1.y,
                                    ma.z*B0.z + ma.w*B1.z, ma.z*B0.w + ma.w*B1.w);
            o0[q] = make_float4(m2.x*ca.x + m2.y*cb.x, m2.x*ca.y + m2.y*cb.y,
                                m2.x*ca.z + m2.y*cb.z, m2.x*ca.w + m2.y*cb.w);
            o1[q] = make_float4(m2.z*ca.x + m2.w*cb.x, m2.z*ca.y + m2.w*cb.y,
                                m2.z*ca.z + m2.w*cb.z, m2.z*ca.w + m2.w*cb.w);
        }
        {   // prefetch next pair's indices (pair fp+1, valid up to 5)
            const int4v* inext = fidx + (size_t)(fp + 1) * 2048;
            #pragma unroll
            for (int q = 0; q < 8; ++q) iN[q] = inext[t + q * 256];
        }
        __syncthreads();
        #pragma unroll
        for (int q = 0; q < 8; ++q) {
            const int k = t + q * 256;
            buf[k]        = o0[q];
            buf[k + 2048] = o1[q];
        }
        __syncthreads();
    }

    // fused pair 5 (rounds 10+11) fused with the store: compute in registers,
    // store directly — bit-identical to LDS round-trip + re-read.
    float lmin = __FLT_MAX__, lmax = -__FLT_MAX__;
    {
        const float4* ap = fmaC + (size_t)5 * 2048;
        const float4* mp = fm2  + (size_t)5 * 2048;
        #pragma unroll
        for (int q = 0; q < 8; ++q) {
            const int k = t + q * 256;
            int4v ix = iN[q];
            float4 A0 = buf[ix[0]], A1 = buf[ix[1]];
            float4 B0 = buf[ix[2]], B1 = buf[ix[3]];
            float4 ma = ap[k], m2 = mp[k];
            float4 ca = make_float4(ma.x*A0.x + ma.y*A1.x, ma.x*A0.y + ma.y*A1.y,
                                    ma.x*A0.z + ma.y*A1.z, ma.x*A0.w + ma.y*A1.w);
            float4 cb = make_float4(ma.z*B0.x + ma.w*B1.x, ma.z*B0.y + ma.w*B1.y,
                                    ma.z*B0.z + ma.w*B1.z, ma.z*B0.w + ma.w*B1.w);
            float4 f0 = make_float4(m2.x*ca.x + m2.y*cb.x, m2.x*ca.y + m2.y*cb.y,
                                    m2.x*ca.z + m2.y*cb.z, m2.x*ca.w + m2.y*cb.w);
            float4 f1 = make_float4(m2.z*ca.x + m2.w*cb.x, m2.z*ca.y + m2.w*cb.y,
                                    m2.z*ca.z + m2.w*cb.z, m2.z*ca.w + m2.w*cb.w);
            lmin = fminf(lmin, fminf(fminf(f0.x, f0.y), fminf(f0.z, f0.w)));
            lmin = fminf(lmin, fminf(fminf(f1.x, f1.y), fminf(f1.z, f1.w)));
            lmax = fmaxf(lmax, fmaxf(fmaxf(f0.x, f0.y), fmaxf(f0.z, f0.w)));
            lmax = fmaxf(lmax, fmaxf(fmaxf(f1.x, f1.y), fmaxf(f1.z, f1.w)));
            const int e = t + q * 256;
            ((float2*)(dst + (r0 + 0) * F_DIM))[e] = make_float2(f0.x, f1.x);
            ((float2*)(dst + (r0 + 1) * F_DIM))[e] = make_float2(f0.y, f1.y);
            ((float2*)(dst + (r0 + 2) * F_DIM))[e] = make_float2(f0.z, f1.z);
            ((float2*)(dst + (r0 + 3) * F_DIM))[e] = make_float2(f0.w, f1.w);
        }
    }
    #pragma unroll
    for (int off = 32; off > 0; off >>= 1) {
        lmin = fminf(lmin, __shfl_down(lmin, off));
        lmax = fmaxf(lmax, __shfl_down(lmax, off));
    }
    if ((t & 63) == 0) {
        atomicMin(&mmp[0], ordf(lmin));
        atomicMax(&mmp[1], ordf(lmax));
    }
}

// ---------------------------------------------------------------------------
// Quantize one row per block from exact fp32: p = clip(rint((f-lo)/scale),0,255)
// (IEEE div + RNE = jnp.round path, validated previously). Store s8 = p-128 and
// the integer row-sum of s8 (needed by the i8 GEMM epilogue).
// ---------------------------------------------------------------------------
__global__ __launch_bounds__(256)
void quant_row_kernel(const float* __restrict__ src,
                      schar*       __restrict__ dst,
                      int*         __restrict__ rowsum,
                      const unsigned* __restrict__ mm, int sel)
{
    const int row = blockIdx.x, t = threadIdx.x;
    const float lo = unordf(mm[sel]);
    const float hi = unordf(mm[sel + 1]);
    const float scale = (hi - lo) / 255.0f;
    const float4* s = (const float4*)(src + (size_t)row * F_DIM);
    unsigned* d = (unsigned*)(dst + (size_t)row * F_DIM);
    int sum = 0;
    #pragma unroll
    for (int j = 0; j < 4; ++j) {
        const int c = t + 256 * j;
        float4 v = s[c];
        int p0 = (int)fminf(fmaxf(rintf((v.x - lo) / scale), 0.0f), 255.0f);
        int p1 = (int)fminf(fmaxf(rintf((v.y - lo) / scale), 0.0f), 255.0f);
        int p2 = (int)fminf(fmaxf(rintf((v.z - lo) / scale), 0.0f), 255.0f);
        int p3 = (int)fminf(fmaxf(rintf((v.w - lo) / scale), 0.0f), 255.0f);
        sum += p0 + p1 + p2 + p3 - 512;   // Σ (p-128)
        unsigned pack = ((unsigned)(p0 - 128) & 0xffu)
                      | (((unsigned)(p1 - 128) & 0xffu) << 8)
                      | (((unsigned)(p2 - 128) & 0xffu) << 16)
                      | (((unsigned)(p3 - 128) & 0xffu) << 24);
        d[c] = pack;
    }
    #pragma unroll
    for (int off = 32; off > 0; off >>= 1) sum += __shfl_down(sum, off);
    __shared__ int part[4];
    if ((t & 63) == 0) part[t >> 6] = sum;
    __syncthreads();
    if (t == 0) rowsum[row] = part[0] + part[1] + part[2] + part[3];
}

// ---------------------------------------------------------------------------
// i8 GEMM: C = dequant(A) * dequant(B)^T + bias, expanded exactly:
//   C[m,n] = ax*aw*Σ sx*sw + ax*cw*Rx[m] + aw*cx*Rw[n] + K*cx*cw + bias[n]
// 128x128 tile, BK2=128 (identical 128 B row-slice / 16 B-chunk XOR-swizzled
// LDS byte layout as the proven bf16 BK=64 kernel; NIT halves to 32).
// mfma_i32_16x16x64_i8: lane l holds A row=l&15, k=(l>>4)*16+j (16 B).
// ---------------------------------------------------------------------------
__global__ __launch_bounds__(256)
void gemm_i8_bias_kernel(const schar* __restrict__ A,
                         const schar* __restrict__ B,
                         const float* __restrict__ bias,
                         const int*   __restrict__ Rx,
                         const int*   __restrict__ Rw,
                         const unsigned* __restrict__ mm,
                         float*       __restrict__ C)
{
    __shared__ alignas(16) schar As[128 * 8 * 16];  // 16 KB: slot = row*8 + c
    __shared__ alignas(16) schar Bs[128 * 8 * 16];  // 16 KB
    const int t = threadIdx.x;
    // supertile: 8 consecutive mb x 32 nb per 256-block group
    const int bid = blockIdx.x;
    const int mb = (bid >> 8) * 8 + (bid & 7);
    const int nb = (bid >> 3) & 31;
    const int lane = t & 63, wv = t >> 6;
    const int wm = (wv & 1) * 64, wn = (wv >> 1) * 64;
    const int rr = lane & 15, kc = lane >> 4;

    const int srow = t >> 3;                     // row within 32-row group
    const int cg   = (t & 7) ^ (srow & 7);       // global 16B chunk (swizzled)
    const schar* pa = A + ((size_t)(mb * 128 + srow) * GK) + cg * 16;
    const schar* pb = B + ((size_t)(nb * 128 + srow) * GK) + cg * 16;

    int4v acc[4][4];
    const int4v zz = {0, 0, 0, 0};
    #pragma unroll
    for (int mi = 0; mi < 4; ++mi)
        #pragma unroll
        for (int ni = 0; ni < 4; ++ni)
            acc[mi][ni] = zz;

    auto stage = [&](int k0) {
        #pragma unroll
        for (int j = 0; j < 4; ++j) {
            __builtin_amdgcn_global_load_lds(
                (glob_void*)(pa + (size_t)j * 32 * GK + k0),
                (lds_void*)&As[(size_t)(wv * 64 + 256 * j) * 16], 16, 0, 0);
            __builtin_amdgcn_global_load_lds(
                (glob_void*)(pb + (size_t)j * 32 * GK + k0),
                (lds_void*)&Bs[(size_t)(wv * 64 + 256 * j) * 16], 16, 0, 0);
        }
    };

    stage(0);
    #pragma unroll 1
    for (int it = 0; it < NIT2; ++it) {
        __syncthreads();   // staging of tile `it` complete

        int4v af[2][4], bfr[2][4];
        #pragma unroll
        for (int kk = 0; kk < 2; ++kk) {
            #pragma unroll
            for (int mi = 0; mi < 4; ++mi)
                af[kk][mi] = *(const int4v*)
                    &As[(size_t)((wm + mi * 16 + rr) * 8 + ((kk * 4 + kc) ^ (rr & 7))) * 16];
            #pragma unroll
            for (int ni = 0; ni < 4; ++ni)
                bfr[kk][ni] = *(const int4v*)
                    &Bs[(size_t)((wn + ni * 16 + rr) * 8 + ((kk * 4 + kc) ^ (rr & 7))) * 16];
        }
        __syncthreads();   // all waves done reading -> LDS free for restage

        if (it + 1 < NIT2) stage((it + 1) * BK2);   // hides under MFMAs below

        #pragma unroll
        for (int kk = 0; kk < 2; ++kk)
            #pragma unroll
            for (int mi = 0; mi < 4; ++mi)
                #pragma unroll
                for (int ni = 0; ni < 4; ++ni)
                    acc[mi][ni] = __builtin_amdgcn_mfma_i32_16x16x64_i8(
                        af[kk][mi], bfr[kk][ni], acc[mi][ni], 0, 0, 0);
    }

    // epilogue: dequant expansion in fp32
    const float lox = unordf(mm[0]), hix = unordf(mm[1]);
    const float low = unordf(mm[2]), hiw = unordf(mm[3]);
    const float ax = (hix - lox) / 255.0f, aw = (hiw - low) / 255.0f;
    const float cx = 128.0f * ax + lox, cw = 128.0f * aw + low;
    const float sxw = ax * aw;
    const float kcc = (float)GK * cx * cw;
    const float axcw = ax * cw, awcx = aw * cx;

    float colt[4];
    #pragma unroll
    for (int ni = 0; ni < 4; ++ni) {
        const int col = nb * 128 + wn + ni * 16 + rr;
        colt[ni] = awcx * (float)Rw[col] + kcc + bias[col];
    }
    float rowt[4][4];
    #pragma unroll
    for (int mi = 0; mi < 4; ++mi)
        #pragma unroll
        for (int r = 0; r < 4; ++r)
            rowt[mi][r] = axcw * (float)Rx[mb * 128 + wm + mi * 16 + kc * 4 + r];

    // C/D layout: row-in-16 = kc*4 + reg, col-in-16 = rr (dtype-independent)
    #pragma unroll
    for (int mi = 0; mi < 4; ++mi) {
        #pragma unroll
        for (int ni = 0; ni < 4; ++ni) {
            const int col = nb * 128 + wn + ni * 16 + rr;
            #pragma unroll
            for (int r = 0; r < 4; ++r) {
                const int row = mb * 128 + wm + mi * 16 + kc * 4 + r;
                C[(size_t)row * GN + col] =
                    sxw * (float)acc[mi][ni][r] + rowt[mi][r] + colt[ni];
            }
        }
    }
}

extern "C" void kernel_launch(void* const* d_in, const int* in_sizes, int n_in,
                              void* d_out, int out_size, void* d_ws, size_t ws_size,
                              hipStream_t stream)
{
    (void)in_sizes; (void)n_in; (void)out_size; (void)ws_size;
    const float* x     = (const float*)d_in[0];
    const float* w     = (const float*)d_in[1];
    const float* bias  = (const float*)d_in[2];
    const float* mats  = (const float*)d_in[3];
    const int*   perms = (const int*)d_in[4];
    float* out = (float*)d_out;

    // ws layout (<= 96 MiB budget, proven):
    //   [0,64M):   w_rot fp32 (64 MiB), dead after quant_w; then reused:
    //              [0,32M) xq8 int8, [32M,+32K) Rx
    //   [64M,80M): wq8 int8 (16 MiB)
    //   [80M,+16K): Rw
    //   [81M,+16B): mm
    //   [82M,+576K): fused round-pair metadata (fidx | fmaC | fm2)
    // d_out: x_rot fp32 (exactly 128 MiB), dead after quant_x; GEMM writes C.
    char* ws = (char*)d_ws;
    float*    wrot = (float*)ws;
    schar*    xq8  = (schar*)ws;
    int*      Rx   = (int*)(ws + (size_t)32 * 1024 * 1024);
    schar*    wq8  = (schar*)(ws + (size_t)64 * 1024 * 1024);
    int*      Rw   = (int*)(ws + (size_t)80 * 1024 * 1024);
    unsigned* mm   = (unsigned*)(ws + (size_t)81 * 1024 * 1024);
    int4v*    fidx = (int4v*)(ws + (size_t)82 * 1024 * 1024);
    float4*   fmaC = (float4*)((char*)fidx + 6 * 2048 * sizeof(int4v));
    float4*   fm2  = (float4*)((char*)fmaC + 6 * 2048 * sizeof(float4));
    float*    xrot = out;

    init_mm_kernel<<<1, 64, 0, stream>>>(mm);
    fuse_meta_kernel<<<(6 * 2048) / 256, 256, 0, stream>>>(perms, mats, fidx, fmaC, fm2);
    // combined W+X rotate: blocks [0, GN/4) = W, [GN/4, GN/4+GM/4) = X
    rotate_store_kernel<<<GN / 4 + GM / 4, 256, 0, stream>>>(
        x, w, fidx, fmaC, fm2, mm, xrot, wrot);
    // quant_w first: it reads wrot before quant_x overwrites that region (xq8)
    quant_row_kernel<<<GN, 256, 0, stream>>>(wrot, wq8, Rw, mm, 2);
    quant_row_kernel<<<GM, 256, 0, stream>>>(xrot, xq8, Rx, mm, 0);
    gemm_i8_bias_kernel<<<GM / 128 * GN / 128, 256, 0, stream>>>(
        xq8, wq8, bias, Rx, Rw, mm, out);
}